// Round 1
// baseline (240.292 us; speedup 1.0000x reference)
//
#include <hip/hip_runtime.h>

#define HH 384
#define WW 384
#define HW (HH * WW)          // 147456
#define NIMG 128              // B*G
#define NPIX (NIMG * HW)      // 18874368
#define NBLK_K1 (NPIX / 256)  // 73728
#define NTILE 576             // 24*24 tiles of 16x16
#define NBLK_K3 (NIMG * NTILE) // 73728
// grad element counts: dx: 128*2*384*383, dy same
#define GRAD_CNT 37650432.0

// ---- block reduction (256 threads = 4 waves) -------------------------------
__device__ inline void block_reduce_store_256(float v, float* dst) {
    #pragma unroll
    for (int o = 32; o > 0; o >>= 1) v += __shfl_down(v, o);
    __shared__ float s[4];
    int wave = threadIdx.x >> 6, lane = threadIdx.x & 63;
    if (lane == 0) s[wave] = v;
    __syncthreads();
    if (threadIdx.x == 0) *dst = s[0] + s[1] + s[2] + s[3];
}

// ---- K1: bilinear warp + grad2d partial sums -------------------------------
__global__ __launch_bounds__(256) void warp_grad_kernel(
        const float* __restrict__ images, const float* __restrict__ warps,
        float* __restrict__ warped, float* __restrict__ partialsG) {
    int gid = blockIdx.x * 256 + threadIdx.x;      // < NPIX exactly
    int n = gid / HW;
    int pix = gid - n * HW;
    int y = pix / WW;
    int x = pix - y * WW;

    const float* flow = warps + (size_t)n * 2 * HW;
    float f0 = flow[pix];        // x displacement (channel 0)
    float f1 = flow[HW + pix];   // y displacement (channel 1)

    // grad2d l2 contributions (zero where no neighbor)
    float g = 0.f;
    if (x < WW - 1) {
        float d0 = flow[pix + 1] - f0;
        float d1 = flow[HW + pix + 1] - f1;
        g += d0 * d0 + d1 * d1;
    }
    if (y < HH - 1) {
        float d0 = flow[pix + WW] - f0;
        float d1 = flow[HW + pix + WW] - f1;
        g += d0 * d0 + d1 * d1;
    }

    // bilinear sample, border-clamped indices (map_coordinates mode="nearest")
    float cx = (float)x + f0;
    float cy = (float)y + f1;
    float fx = floorf(cx), fy = floorf(cy);
    float wx = cx - fx,   wy = cy - fy;
    int x0 = (int)fx, y0 = (int)fy;
    int x0c = min(max(x0, 0), WW - 1);
    int x1c = min(max(x0 + 1, 0), WW - 1);
    int y0c = min(max(y0, 0), HH - 1);
    int y1c = min(max(y0 + 1, 0), HH - 1);

    const float* img = images + (size_t)n * HW;
    float v00 = img[y0c * WW + x0c], v01 = img[y0c * WW + x1c];
    float v10 = img[y1c * WW + x0c], v11 = img[y1c * WW + x1c];
    float top = v00 + wx * (v01 - v00);
    float bot = v10 + wx * (v11 - v10);
    warped[gid] = top + wy * (bot - top);

    block_reduce_store_256(g, &partialsG[blockIdx.x]);
}

// ---- K2: template = mean over N --------------------------------------------
__global__ __launch_bounds__(256) void template_kernel(
        const float* __restrict__ warped, float* __restrict__ templ) {
    int pix = blockIdx.x * 256 + threadIdx.x;      // < HW exactly
    float s = 0.f;
    #pragma unroll 4
    for (int n = 0; n < NIMG; ++n) s += warped[(size_t)n * HW + pix];
    templ[pix] = s * (1.f / (float)NIMG);
}

// ---- K3: LNCC per (n, tile), 16x16 tile + halo in LDS ----------------------
__global__ __launch_bounds__(256) void lncc_kernel(
        const float* __restrict__ warped, const float* __restrict__ templ,
        float* __restrict__ partialsN) {
    __shared__ float st[18][20];
    __shared__ float sp[18][20];
    int tile = blockIdx.x;                 // 0..575
    int n = blockIdx.y;                    // 0..127
    int ty0 = (tile / 24) * 16, tx0 = (tile % 24) * 16;
    const float* t = warped + (size_t)n * HW;
    int tid = threadIdx.x;

    for (int i = tid; i < 18 * 18; i += 256) {
        int ly = i / 18, lx = i - ly * 18;
        int gy = ty0 + ly - 1, gx = tx0 + lx - 1;
        bool ok = (gy >= 0) & (gy < HH) & (gx >= 0) & (gx < WW);
        int gidx = gy * WW + gx;
        st[ly][lx] = ok ? t[gidx] : 0.f;
        sp[ly][lx] = ok ? templ[gidx] : 0.f;
    }
    __syncthreads();

    int ty = tid >> 4, tx = tid & 15;
    float ts = 0, ps = 0, t2 = 0, p2 = 0, tp = 0;
    #pragma unroll
    for (int dy = 0; dy < 3; ++dy) {
        #pragma unroll
        for (int dx = 0; dx < 3; ++dx) {
            float tv = st[ty + dy][tx + dx];
            float pv = sp[ty + dy][tx + dx];
            ts += tv; ps += pv;
            t2 = fmaf(tv, tv, t2);
            p2 = fmaf(pv, pv, p2);
            tp = fmaf(tv, pv, tp);
        }
    }
    const float inv9 = 1.f / 9.f;
    float cross = tp - (ps * inv9) * ts;
    float tvar = fmaxf(t2 - (ts * inv9) * ts, 0.f);
    float pvar = fmaxf(p2 - (ps * inv9) * ps, 0.f);
    float ncc = (cross * cross) / (tvar * pvar + 1e-5f);

    block_reduce_store_256(ncc, &partialsN[n * NTILE + tile]);
}

// ---- K4: final reduction (double) ------------------------------------------
__global__ __launch_bounds__(1024) void finalize_kernel(
        const float* __restrict__ pN, const float* __restrict__ pG,
        float* __restrict__ out) {
    double accN = 0.0, accG = 0.0;
    for (int i = threadIdx.x; i < NBLK_K3; i += 1024) {
        accN += (double)pN[i];
        accG += (double)pG[i];
    }
    #pragma unroll
    for (int o = 32; o > 0; o >>= 1) {
        accN += __shfl_down(accN, o);
        accG += __shfl_down(accG, o);
    }
    __shared__ double sN[16], sG[16];
    int wave = threadIdx.x >> 6, lane = threadIdx.x & 63;
    if (lane == 0) { sN[wave] = accN; sG[wave] = accG; }
    __syncthreads();
    if (threadIdx.x == 0) {
        double tN = 0.0, tG = 0.0;
        #pragma unroll
        for (int w = 0; w < 16; ++w) { tN += sN[w]; tG += sG[w]; }
        double lncc = -(tN / (double)NPIX);
        double g2 = tG / (2.0 * GRAD_CNT);
        out[0] = (float)(lncc + g2);
    }
}

extern "C" void kernel_launch(void* const* d_in, const int* in_sizes, int n_in,
                              void* d_out, int out_size, void* d_ws, size_t ws_size,
                              hipStream_t stream) {
    const float* images = (const float*)d_in[0];
    const float* warps  = (const float*)d_in[1];
    float* out = (float*)d_out;

    float* ws = (float*)d_ws;
    float* warped   = ws;                         // NPIX floats
    float* templ    = warped + NPIX;              // HW floats
    float* partialsN = templ + HW;                // NBLK_K3 floats
    float* partialsG = partialsN + NBLK_K3;       // NBLK_K1 floats

    warp_grad_kernel<<<dim3(NBLK_K1), dim3(256), 0, stream>>>(
        images, warps, warped, partialsG);
    template_kernel<<<dim3(HW / 256), dim3(256), 0, stream>>>(warped, templ);
    lncc_kernel<<<dim3(NTILE, NIMG), dim3(256), 0, stream>>>(
        warped, templ, partialsN);
    finalize_kernel<<<dim3(1), dim3(1024), 0, stream>>>(
        partialsN, partialsG, out);
}

// Round 2
// 161.574 us; speedup vs baseline: 1.4872x; 1.4872x over previous
//
#include <hip/hip_runtime.h>

#define HH 384
#define WW 384
#define HW (HH * WW)            // 147456
#define NIMG 128                // B*G
#define NPIX (NIMG * HW)        // 18874368
#define GRAD_CNT 37650432.0

// K1 tiling: 128 wide x 8 high, 256 threads, 4 px/thread (float4)
#define K1_TW 128
#define K1_TH 8
#define K1_TX (WW / K1_TW)          // 3
#define K1_TY (HH / K1_TH)          // 48
#define K1_TILES (K1_TX * K1_TY)    // 144
#define NP_G (K1_TILES * NIMG)      // 18432

// K3 tiling: 32x32 tiles, 256 threads, 4 px/thread
#define K3_T 32
#define K3_NX (WW / K3_T)           // 12
#define K3_TILES (K3_NX * (HH / K3_T)) // 144
#define NP_N (K3_TILES * NIMG)      // 18432

// ---- block reduction (256 threads = 4 waves) -------------------------------
__device__ inline void block_reduce_store_256(float v, float* dst) {
    #pragma unroll
    for (int o = 32; o > 0; o >>= 1) v += __shfl_down(v, o);
    __shared__ float s[4];
    int wave = threadIdx.x >> 6, lane = threadIdx.x & 63;
    if (lane == 0) s[wave] = v;
    __syncthreads();
    if (threadIdx.x == 0) *dst = s[0] + s[1] + s[2] + s[3];
}

// ---- K1: bilinear warp + grad2d partial sums (2D tiled, vectorized) --------
__global__ __launch_bounds__(256) void warp_grad_kernel(
        const float* __restrict__ images, const float* __restrict__ warps,
        float* __restrict__ warped, float* __restrict__ partialsG) {
    int n = blockIdx.y;
    int tile = blockIdx.x;
    int ty_t = tile / K1_TX, tx_t = tile - ty_t * K1_TX;
    int lane_x = threadIdx.x & 31;
    int rrow   = threadIdx.x >> 5;
    int x0 = tx_t * K1_TW + lane_x * 4;
    int y  = ty_t * K1_TH + rrow;

    const float* flow0 = warps + (size_t)n * 2 * HW + y * WW + x0;
    const float* flow1 = flow0 + HW;
    float4 f0 = *(const float4*)flow0;
    float4 f1 = *(const float4*)flow1;
    bool hasR = (x0 + 4 < WW);
    float f0n = hasR ? flow0[4] : 0.f;
    float f1n = hasR ? flow1[4] : 0.f;

    float g = 0.f;
    if (y + 1 < HH) {                       // dy terms (4 px, both channels)
        float4 b0 = *(const float4*)(flow0 + WW);
        float4 b1 = *(const float4*)(flow1 + WW);
        float d;
        d = b0.x - f0.x; g += d * d;  d = b1.x - f1.x; g += d * d;
        d = b0.y - f0.y; g += d * d;  d = b1.y - f1.y; g += d * d;
        d = b0.z - f0.z; g += d * d;  d = b1.z - f1.z; g += d * d;
        d = b0.w - f0.w; g += d * d;  d = b1.w - f1.w; g += d * d;
    }
    {                                       // dx terms
        float d;
        d = f0.y - f0.x; g += d * d;  d = f1.y - f1.x; g += d * d;
        d = f0.z - f0.y; g += d * d;  d = f1.z - f1.y; g += d * d;
        d = f0.w - f0.z; g += d * d;  d = f1.w - f1.z; g += d * d;
        if (hasR) { d = f0n - f0.w; g += d * d;  d = f1n - f1.w; g += d * d; }
    }

    const float* img = images + (size_t)n * HW;
    float fx[4] = {f0.x, f0.y, f0.z, f0.w};
    float fy[4] = {f1.x, f1.y, f1.z, f1.w};
    float4 outv;
    float* o = (float*)&outv;
    #pragma unroll
    for (int j = 0; j < 4; ++j) {
        float cx = (float)(x0 + j) + fx[j];
        float cy = (float)y + fy[j];
        float flx = floorf(cx), fly = floorf(cy);
        float wx = cx - flx, wy = cy - fly;
        int xi = (int)flx, yi = (int)fly;
        int x0c = min(max(xi, 0), WW - 1), x1c = min(max(xi + 1, 0), WW - 1);
        int y0c = min(max(yi, 0), HH - 1), y1c = min(max(yi + 1, 0), HH - 1);
        float v00 = img[y0c * WW + x0c], v01 = img[y0c * WW + x1c];
        float v10 = img[y1c * WW + x0c], v11 = img[y1c * WW + x1c];
        float top = v00 + wx * (v01 - v00);
        float bot = v10 + wx * (v11 - v10);
        o[j] = top + wy * (bot - top);
    }
    *(float4*)(warped + (size_t)n * HW + y * WW + x0) = outv;

    block_reduce_store_256(g, &partialsG[(size_t)n * K1_TILES + tile]);
}

// ---- K2: template = mean over N --------------------------------------------
__global__ __launch_bounds__(256) void template_kernel(
        const float* __restrict__ warped, float* __restrict__ templ) {
    int pix = blockIdx.x * 256 + threadIdx.x;      // 576 blocks, < HW exactly
    const float* p = warped + pix;
    float s = 0.f;
    #pragma unroll 8
    for (int nn = 0; nn < NIMG; ++nn) s += p[(size_t)nn * HW];
    templ[pix] = s * (1.f / (float)NIMG);
}

// ---- K3: LNCC per (n, 32x32 tile), register sliding-window box sums --------
__global__ __launch_bounds__(256) void lncc_kernel(
        const float* __restrict__ warped, const float* __restrict__ templ,
        float* __restrict__ partialsN) {
    __shared__ float st[34][37];
    __shared__ float sp[34][37];
    int n = blockIdx.y;
    int tile = blockIdx.x;
    int tyt = tile / K3_NX, txt = tile - tyt * K3_NX;
    int oy0 = tyt * K3_T, ox0 = txt * K3_T;
    const float* t = warped + (size_t)n * HW;
    int tid = threadIdx.x;

    for (int i = tid; i < 34 * 34; i += 256) {
        int ly = i / 34, lx = i - ly * 34;
        int gy = oy0 + ly - 1, gx = ox0 + lx - 1;
        bool ok = (gy >= 0) & (gy < HH) & (gx >= 0) & (gx < WW);
        int gidx = gy * WW + gx;
        st[ly][lx] = ok ? t[gidx] : 0.f;
        sp[ly][lx] = ok ? templ[gidx] : 0.f;
    }
    __syncthreads();

    int tx = tid & 7, ty = tid >> 3;   // ty: output row 0..31, tx*4: x base
    int xb = tx * 4;
    float cT[6], cP[6], cT2[6], cP2[6], cTP[6];
    #pragma unroll
    for (int c = 0; c < 6; ++c) {
        float s1 = 0, s2 = 0, s3 = 0, s4 = 0, s5 = 0;
        #pragma unroll
        for (int r = 0; r < 3; ++r) {
            float tv = st[ty + r][xb + c];
            float pv = sp[ty + r][xb + c];
            s1 += tv; s2 += pv;
            s3 = fmaf(tv, tv, s3); s4 = fmaf(pv, pv, s4); s5 = fmaf(tv, pv, s5);
        }
        cT[c] = s1; cP[c] = s2; cT2[c] = s3; cP2[c] = s4; cTP[c] = s5;
    }
    const float inv9 = 1.f / 9.f;
    float nccsum = 0.f;
    #pragma unroll
    for (int j = 0; j < 4; ++j) {
        float ts = cT[j] + cT[j + 1] + cT[j + 2];
        float ps = cP[j] + cP[j + 1] + cP[j + 2];
        float t2 = cT2[j] + cT2[j + 1] + cT2[j + 2];
        float p2 = cP2[j] + cP2[j + 1] + cP2[j + 2];
        float tp = cTP[j] + cTP[j + 1] + cTP[j + 2];
        float cross = tp - (ps * inv9) * ts;
        float tvar = fmaxf(t2 - (ts * inv9) * ts, 0.f);
        float pvar = fmaxf(p2 - (ps * inv9) * ps, 0.f);
        nccsum += (cross * cross) / (tvar * pvar + 1e-5f);
    }
    block_reduce_store_256(nccsum, &partialsN[(size_t)n * K3_TILES + tile]);
}

// ---- K4: final reduction (double) ------------------------------------------
__global__ __launch_bounds__(1024) void finalize_kernel(
        const float* __restrict__ pN, const float* __restrict__ pG,
        float* __restrict__ out) {
    double accN = 0.0, accG = 0.0;
    for (int i = threadIdx.x; i < NP_N; i += 1024) {
        accN += (double)pN[i];
        accG += (double)pG[i];
    }
    #pragma unroll
    for (int o = 32; o > 0; o >>= 1) {
        accN += __shfl_down(accN, o);
        accG += __shfl_down(accG, o);
    }
    __shared__ double sN[16], sG[16];
    int wave = threadIdx.x >> 6, lane = threadIdx.x & 63;
    if (lane == 0) { sN[wave] = accN; sG[wave] = accG; }
    __syncthreads();
    if (threadIdx.x == 0) {
        double tN = 0.0, tG = 0.0;
        #pragma unroll
        for (int w = 0; w < 16; ++w) { tN += sN[w]; tG += sG[w]; }
        double lncc = -(tN / (double)NPIX);
        double g2 = tG / (2.0 * GRAD_CNT);
        out[0] = (float)(lncc + g2);
    }
}

extern "C" void kernel_launch(void* const* d_in, const int* in_sizes, int n_in,
                              void* d_out, int out_size, void* d_ws, size_t ws_size,
                              hipStream_t stream) {
    const float* images = (const float*)d_in[0];
    const float* warps  = (const float*)d_in[1];
    float* out = (float*)d_out;

    float* ws = (float*)d_ws;
    float* warped    = ws;                        // NPIX floats
    float* templ     = warped + NPIX;             // HW floats
    float* partialsN = templ + HW;                // NP_N floats
    float* partialsG = partialsN + NP_N;          // NP_G floats

    warp_grad_kernel<<<dim3(K1_TILES, NIMG), dim3(256), 0, stream>>>(
        images, warps, warped, partialsG);
    template_kernel<<<dim3(HW / 256), dim3(256), 0, stream>>>(warped, templ);
    lncc_kernel<<<dim3(K3_TILES, NIMG), dim3(256), 0, stream>>>(
        warped, templ, partialsN);
    finalize_kernel<<<dim3(1), dim3(1024), 0, stream>>>(
        partialsN, partialsG, out);
}

// Round 3
// 158.753 us; speedup vs baseline: 1.5136x; 1.0178x over previous
//
#include <hip/hip_runtime.h>

#define HH 384
#define WW 384
#define HW (HH * WW)            // 147456
#define NIMG 128                // B*G
#define NPIX (NIMG * HW)        // 18874368
#define GRAD_CNT 37650432.0

// K1: full-width tiles, 16 rows, +/-6 row staged margin
#define K1_TH 16
#define K1_M  6
#define K1_NT (HH / K1_TH)              // 24
#define K1_SROWS (K1_TH + 2 * K1_M)     // 28
#define K1_LS 388                       // LDS row stride (16B-aligned, bank-spread)
#define NP_G (K1_NT * NIMG)             // 3072

// K3 tiling: 32x32 tiles, 256 threads, 4 px/thread
#define K3_T 32
#define K3_NX (WW / K3_T)               // 12
#define K3_TILES (K3_NX * (HH / K3_T))  // 144
#define NP_N (K3_TILES * NIMG)          // 18432

// ---- block reduction (256 threads = 4 waves) -------------------------------
__device__ inline void block_reduce_store_256(float v, float* dst) {
    #pragma unroll
    for (int o = 32; o > 0; o >>= 1) v += __shfl_down(v, o);
    __shared__ float s[4];
    int wave = threadIdx.x >> 6, lane = threadIdx.x & 63;
    if (lane == 0) s[wave] = v;
    __syncthreads();
    if (threadIdx.x == 0) *dst = s[0] + s[1] + s[2] + s[3];
}

// ---- K1: bilinear warp (LDS-staged gather) + grad2d partial sums -----------
__global__ __launch_bounds__(256) void warp_grad_kernel(
        const float* __restrict__ images, const float* __restrict__ warps,
        float* __restrict__ warped, float* __restrict__ partialsG) {
    __shared__ float simg[K1_SROWS * K1_LS];
    int n = blockIdx.y;
    int yt = blockIdx.x;
    int y0 = yt * K1_TH;
    int ys0 = max(0, y0 - K1_M);
    int ys1 = min(HH - 1, y0 + K1_TH - 1 + K1_M);
    int cnt = ys1 - ys0 + 1;                  // <= 28
    const float* img = images + (size_t)n * HW;
    int tid = threadIdx.x;

    // stage rows [ys0, ys1] as coalesced float4 streams
    for (int i = tid; i < cnt * 96; i += 256) {
        int r = i / 96, c4 = i - r * 96;
        float4 v = *(const float4*)(img + (ys0 + r) * WW + c4 * 4);
        *(float4*)(simg + r * K1_LS + c4 * 4) = v;
    }
    __syncthreads();

    const float* flow0 = warps + (size_t)n * 2 * HW;
    const float* flow1 = flow0 + HW;
    float g = 0.f;

    #pragma unroll
    for (int gi = 0; gi < 6; ++gi) {
        int p4 = gi * 256 + tid;              // 0..1535 float4 groups
        int r = p4 / 96;                      // tile row 0..15
        int c4 = p4 - r * 96;
        int x0 = c4 * 4;
        int y = y0 + r;
        int base = y * WW + x0;

        float4 f0 = *(const float4*)(flow0 + base);
        float4 f1 = *(const float4*)(flow1 + base);

        // grad2d l2: dx within group + right neighbor, dy vs next row
        float d;
        d = f0.y - f0.x; g += d * d;  d = f1.y - f1.x; g += d * d;
        d = f0.z - f0.y; g += d * d;  d = f1.z - f1.y; g += d * d;
        d = f0.w - f0.z; g += d * d;  d = f1.w - f1.z; g += d * d;
        if (x0 + 4 < WW) {
            float a0 = flow0[base + 4], a1 = flow1[base + 4];
            d = a0 - f0.w; g += d * d;  d = a1 - f1.w; g += d * d;
        }
        if (y + 1 < HH) {
            float4 b0 = *(const float4*)(flow0 + base + WW);
            float4 b1 = *(const float4*)(flow1 + base + WW);
            d = b0.x - f0.x; g += d * d;  d = b1.x - f1.x; g += d * d;
            d = b0.y - f0.y; g += d * d;  d = b1.y - f1.y; g += d * d;
            d = b0.z - f0.z; g += d * d;  d = b1.z - f1.z; g += d * d;
            d = b0.w - f0.w; g += d * d;  d = b1.w - f1.w; g += d * d;
        }

        float fxa[4] = {f0.x, f0.y, f0.z, f0.w};
        float fya[4] = {f1.x, f1.y, f1.z, f1.w};
        float4 outv; float* o = (float*)&outv;
        #pragma unroll
        for (int j = 0; j < 4; ++j) {
            float cx = (float)(x0 + j) + fxa[j];
            float cy = (float)y + fya[j];
            float flx = floorf(cx), fly = floorf(cy);
            float wx = cx - flx, wy = cy - fly;
            int xi = (int)flx, yi = (int)fly;
            int x0c = min(max(xi, 0), WW - 1), x1c = min(max(xi + 1, 0), WW - 1);
            int y0c = min(max(yi, 0), HH - 1), y1c = min(max(yi + 1, 0), HH - 1);
            float v00, v01, v10, v11;
            if (y0c >= ys0 && y1c <= ys1) {        // ~always: LDS gather
                const float* r0 = simg + (y0c - ys0) * K1_LS;
                const float* r1 = simg + (y1c - ys0) * K1_LS;
                v00 = r0[x0c]; v01 = r0[x1c];
                v10 = r1[x0c]; v11 = r1[x1c];
            } else {                               // rare: exact global fallback
                v00 = img[y0c * WW + x0c]; v01 = img[y0c * WW + x1c];
                v10 = img[y1c * WW + x0c]; v11 = img[y1c * WW + x1c];
            }
            float top = v00 + wx * (v01 - v00);
            float bot = v10 + wx * (v11 - v10);
            o[j] = top + wy * (bot - top);
        }
        *(float4*)(warped + (size_t)n * HW + base) = outv;
    }
    block_reduce_store_256(g, &partialsG[(size_t)n * K1_NT + yt]);
}

// ---- K2: template = mean over N (float4, unroll 8) -------------------------
__global__ __launch_bounds__(256) void template_kernel(
        const float* __restrict__ warped, float* __restrict__ templ) {
    int p4 = blockIdx.x * 256 + threadIdx.x;      // 144 blocks, < HW/4
    const float* p = warped + p4 * 4;
    float4 s = {0.f, 0.f, 0.f, 0.f};
    #pragma unroll 8
    for (int nn = 0; nn < NIMG; ++nn) {
        float4 v = *(const float4*)(p + (size_t)nn * HW);
        s.x += v.x; s.y += v.y; s.z += v.z; s.w += v.w;
    }
    const float sc = 1.f / (float)NIMG;
    s.x *= sc; s.y *= sc; s.z *= sc; s.w *= sc;
    *(float4*)(templ + p4 * 4) = s;
}

// ---- K3: LNCC per (n, 32x32 tile), register sliding-window box sums --------
__global__ __launch_bounds__(256) void lncc_kernel(
        const float* __restrict__ warped, const float* __restrict__ templ,
        float* __restrict__ partialsN) {
    __shared__ float st[34][37];
    __shared__ float sp[34][37];
    int n = blockIdx.y;
    int tile = blockIdx.x;
    int tyt = tile / K3_NX, txt = tile - tyt * K3_NX;
    int oy0 = tyt * K3_T, ox0 = txt * K3_T;
    const float* t = warped + (size_t)n * HW;
    int tid = threadIdx.x;

    for (int i = tid; i < 34 * 34; i += 256) {
        int ly = i / 34, lx = i - ly * 34;
        int gy = oy0 + ly - 1, gx = ox0 + lx - 1;
        bool ok = (gy >= 0) & (gy < HH) & (gx >= 0) & (gx < WW);
        int gidx = gy * WW + gx;
        st[ly][lx] = ok ? t[gidx] : 0.f;
        sp[ly][lx] = ok ? templ[gidx] : 0.f;
    }
    __syncthreads();

    int tx = tid & 7, ty = tid >> 3;   // ty: output row 0..31, tx*4: x base
    int xb = tx * 4;
    float cT[6], cP[6], cT2[6], cP2[6], cTP[6];
    #pragma unroll
    for (int c = 0; c < 6; ++c) {
        float s1 = 0, s2 = 0, s3 = 0, s4 = 0, s5 = 0;
        #pragma unroll
        for (int r = 0; r < 3; ++r) {
            float tv = st[ty + r][xb + c];
            float pv = sp[ty + r][xb + c];
            s1 += tv; s2 += pv;
            s3 = fmaf(tv, tv, s3); s4 = fmaf(pv, pv, s4); s5 = fmaf(tv, pv, s5);
        }
        cT[c] = s1; cP[c] = s2; cT2[c] = s3; cP2[c] = s4; cTP[c] = s5;
    }
    const float inv9 = 1.f / 9.f;
    float nccsum = 0.f;
    #pragma unroll
    for (int j = 0; j < 4; ++j) {
        float ts = cT[j] + cT[j + 1] + cT[j + 2];
        float ps = cP[j] + cP[j + 1] + cP[j + 2];
        float t2 = cT2[j] + cT2[j + 1] + cT2[j + 2];
        float p2 = cP2[j] + cP2[j + 1] + cP2[j + 2];
        float tp = cTP[j] + cTP[j + 1] + cTP[j + 2];
        float cross = tp - (ps * inv9) * ts;
        float tvar = fmaxf(t2 - (ts * inv9) * ts, 0.f);
        float pvar = fmaxf(p2 - (ps * inv9) * ps, 0.f);
        nccsum += (cross * cross) / (tvar * pvar + 1e-5f);
    }
    block_reduce_store_256(nccsum, &partialsN[(size_t)n * K3_TILES + tile]);
}

// ---- K4: final reduction (double) ------------------------------------------
__global__ __launch_bounds__(1024) void finalize_kernel(
        const float* __restrict__ pN, const float* __restrict__ pG,
        float* __restrict__ out) {
    double accN = 0.0, accG = 0.0;
    for (int i = threadIdx.x; i < NP_N; i += 1024) accN += (double)pN[i];
    for (int i = threadIdx.x; i < NP_G; i += 1024) accG += (double)pG[i];
    #pragma unroll
    for (int o = 32; o > 0; o >>= 1) {
        accN += __shfl_down(accN, o);
        accG += __shfl_down(accG, o);
    }
    __shared__ double sN[16], sG[16];
    int wave = threadIdx.x >> 6, lane = threadIdx.x & 63;
    if (lane == 0) { sN[wave] = accN; sG[wave] = accG; }
    __syncthreads();
    if (threadIdx.x == 0) {
        double tN = 0.0, tG = 0.0;
        #pragma unroll
        for (int w = 0; w < 16; ++w) { tN += sN[w]; tG += sG[w]; }
        double lncc = -(tN / (double)NPIX);
        double g2 = tG / (2.0 * GRAD_CNT);
        out[0] = (float)(lncc + g2);
    }
}

extern "C" void kernel_launch(void* const* d_in, const int* in_sizes, int n_in,
                              void* d_out, int out_size, void* d_ws, size_t ws_size,
                              hipStream_t stream) {
    const float* images = (const float*)d_in[0];
    const float* warps  = (const float*)d_in[1];
    float* out = (float*)d_out;

    float* ws = (float*)d_ws;
    float* warped    = ws;                        // NPIX floats
    float* templ     = warped + NPIX;             // HW floats
    float* partialsN = templ + HW;                // NP_N floats
    float* partialsG = partialsN + NP_N;          // NP_G floats

    warp_grad_kernel<<<dim3(K1_NT, NIMG), dim3(256), 0, stream>>>(
        images, warps, warped, partialsG);
    template_kernel<<<dim3(HW / 4 / 256), dim3(256), 0, stream>>>(warped, templ);
    lncc_kernel<<<dim3(K3_TILES, NIMG), dim3(256), 0, stream>>>(
        warped, templ, partialsN);
    finalize_kernel<<<dim3(1), dim3(1024), 0, stream>>>(
        partialsN, partialsG, out);
}